// Round 2
// baseline (12148.703 us; speedup 1.0000x reference)
//
#include <hip/hip_runtime.h>

// Problem constants
#define B_    32
#define T_    2048
#define F_    64
#define H_    256
#define OUT_  64
#define G3_   768           // 3*H
#define NWG   32            // workgroups in the persistent GRU kernel
#define NITER (T_ + 1)      // pipelined: iter i computes h1[i] and h2[i-1]

// ws layout (bytes)
#define XN_BYTES   (B_ * T_ * F_ * 2)            // 8,388,608  fp16 LN(x), [T][B][F]
#define PACK_OFF   XN_BYTES
#define PACK_ELEMS (B_ * H_)                     // 8192 fp16 per buffer
#define PACK_BYTES (4 * PACK_ELEMS * 2)          // h1[2 parity] + h2[2 parity]
#define CNT_OFF    (PACK_OFF + PACK_BYTES)
#define CNT_LINES  8
#define CNT_STRIDE 16                            // dwords -> 64B line spacing

typedef _Float16 half8 __attribute__((ext_vector_type(8)));
typedef _Float16 half4 __attribute__((ext_vector_type(4)));
typedef float    f32x4 __attribute__((ext_vector_type(4)));

__device__ __forceinline__ float sigf(float x) {
    x = fminf(fmaxf(x, -30.f), 30.f);
    return 1.f / (1.f + __expf(-x));
}
__device__ __forceinline__ float tanhfast(float x) {
    x = fminf(fmaxf(x, -15.f), 15.f);
    float e = __expf(2.f * x);
    return (e - 1.f) / (e + 1.f);
}
__device__ __forceinline__ unsigned short f16b(float f) {
    union { _Float16 h; unsigned short u; } c; c.h = (_Float16)f; return c.u;
}
// Agent-scope coherent 16B pack load (2 x 8B atomic, bypasses L1/L2 -> IC)
__device__ __forceinline__ half8 pack_load16(const _Float16* p) {
    union { unsigned long long q[2]; half8 h; } u;
    u.q[0] = __hip_atomic_load((const unsigned long long*)p,     __ATOMIC_RELAXED, __HIP_MEMORY_SCOPE_AGENT);
    u.q[1] = __hip_atomic_load((const unsigned long long*)p + 1, __ATOMIC_RELAXED, __HIP_MEMORY_SCOPE_AGENT);
    return u.h;
}
// Gather 4 neighboring lanes' fp16 (jl, jl^1, jl^2, jl^3) into one u64 (little-endian by jl)
__device__ __forceinline__ unsigned long long gather4(unsigned short u, int jl) {
    unsigned int p = (unsigned int)__shfl_xor((int)(unsigned int)u, 1);
    unsigned int lo32 = (jl & 1) ? ((p & 0xffffu) | ((unsigned int)u << 16))
                                 : ((unsigned int)u | (p << 16));
    unsigned int q = (unsigned int)__shfl_xor((int)lo32, 2);
    return (jl & 2) ? (((unsigned long long)lo32 << 32) | q)
                    : ((unsigned long long)lo32 | ((unsigned long long)q << 32));
}

// ---------------------------------------------------------------------------
// Init: zero barrier counters + h-pack buffers, out = bias broadcast
// ---------------------------------------------------------------------------
__global__ void init_kernel(float* __restrict__ out, const float* __restrict__ bd,
                            _Float16* __restrict__ packs, unsigned int* __restrict__ cnt) {
    int t = blockIdx.x * 256 + threadIdx.x;              // 16*256 = 4096 threads
    if (t < B_ * OUT_) out[t] = bd[t & (OUT_ - 1)];
    if (t < CNT_LINES * CNT_STRIDE) cnt[t] = 0u;
    for (int p = t; p < 4 * PACK_ELEMS; p += 4096) packs[p] = (_Float16)0.f;
}

// ---------------------------------------------------------------------------
// LayerNorm over F=64, fp16 output TRANSPOSED to [T][B][F].
// 256 threads = 16 rows/block (16 lanes x float4 per row). Grid = B*T/16.
// ---------------------------------------------------------------------------
__global__ __launch_bounds__(256) void ln_kernel(const float* __restrict__ x,
                                                 const float* __restrict__ gamma,
                                                 const float* __restrict__ beta,
                                                 _Float16* __restrict__ xn) {
    const int tid = threadIdx.x;
    const int r = tid >> 4, q = tid & 15;
    const size_t row = (size_t)blockIdx.x * 16 + r;      // = b*T + t
    const int b = (int)(row >> 11);                      // /2048
    const int t = (int)(row & 2047);
    const float4 v  = *(const float4*)(x + row * F_ + q * 4);
    const float4 g  = *(const float4*)(gamma + q * 4);
    const float4 be = *(const float4*)(beta + q * 4);
    float s = v.x + v.y + v.z + v.w;
    s += __shfl_xor(s, 1, 16); s += __shfl_xor(s, 2, 16);
    s += __shfl_xor(s, 4, 16); s += __shfl_xor(s, 8, 16);
    const float mu = s * (1.f / 64.f);
    const float dx = v.x - mu, dy = v.y - mu, dz = v.z - mu, dw = v.w - mu;
    float qq = dx * dx + dy * dy + dz * dz + dw * dw;
    qq += __shfl_xor(qq, 1, 16); qq += __shfl_xor(qq, 2, 16);
    qq += __shfl_xor(qq, 4, 16); qq += __shfl_xor(qq, 8, 16);
    const float rs = rsqrtf(qq * (1.f / 64.f) + 1e-3f);
    half4 o;
    o[0] = (_Float16)(dx * rs * g.x + be.x);
    o[1] = (_Float16)(dy * rs * g.y + be.y);
    o[2] = (_Float16)(dz * rs * g.z + be.z);
    o[3] = (_Float16)(dw * rs * g.w + be.w);
    *(half4*)(xn + ((size_t)t * B_ + b) * F_ + q * 4) = o;
}

// ---------------------------------------------------------------------------
// Persistent fused 2-layer GRU scan + final dense. 32 WGs x 256 (cooperative).
// Cross-WG h-packs move via agent-scope relaxed atomics (write-through to IC):
// no threadfence, no L2 wb/inv. Barrier = 8 monotonic counter lines (4 WGs
// each), polled in parallel by tid<8; target 4*i. One barrier per step.
// ---------------------------------------------------------------------------
__global__ __launch_bounds__(256) void gru_main(
    const _Float16* __restrict__ xn,
    const float* __restrict__ k1, const float* __restrict__ rk1,
    const float* __restrict__ b1, const float* __restrict__ k2,
    const float* __restrict__ rk2, const float* __restrict__ b2,
    const float* __restrict__ wd, float* __restrict__ out,
    _Float16* __restrict__ packs, unsigned int* __restrict__ cnt) {
    const int w    = blockIdx.x;         // 0..31
    const int tid  = threadIdx.x;
    const int lane = tid & 63;
    const int wave = tid >> 6;           // 4 waves: (mt, nt)
    const int mt   = wave & 1;
    const int nt   = wave >> 1;
    const int ln   = lane & 15;
    const int quad = lane >> 4;

    // ---- B-operand fragments (MFMA 16x16x32 f16): lane holds B[k=quad*8+j][n=lane&15]
    const int  lc    = nt * 16 + ln;
    const bool valid = (lc < 24);
    const int  gate  = lc >> 3;
    const int  hidx  = lc & 7;
    const int  gcol  = valid ? (gate * H_ + w * 8 + hidx) : 0;

    half8 fk1[2], frk1[8], fk2[8], frk2[8];
#pragma unroll
    for (int ks = 0; ks < 2; ++ks) {
        half8 f;
#pragma unroll
        for (int j = 0; j < 8; ++j) {
            const int k = ks * 32 + quad * 8 + j;
            const float v = k1[k * G3_ + gcol];
            f[j] = valid ? (_Float16)v : (_Float16)0.f;
        }
        fk1[ks] = f;
    }
#pragma unroll
    for (int ks = 0; ks < 8; ++ks) {
        half8 f1, f2, f3;
#pragma unroll
        for (int j = 0; j < 8; ++j) {
            const int k = ks * 32 + quad * 8 + j;
            const float v1 = rk1[k * G3_ + gcol];
            const float v2 = k2 [k * G3_ + gcol];
            const float v3 = rk2[k * G3_ + gcol];
            f1[j] = valid ? (_Float16)v1 : (_Float16)0.f;
            f2[j] = valid ? (_Float16)v2 : (_Float16)0.f;
            f3[j] = valid ? (_Float16)v3 : (_Float16)0.f;
        }
        frk1[ks] = f1; fk2[ks] = f2; frk2[ks] = f3;
    }

    // ---- gate-phase mapping: (batch bb, local idx jl); owns h[bb][8w+jl] of both layers
    const int jl = tid & 7;
    const int bb = tid >> 3;
    const int gc = w * 8 + jl;
    const float b1xz = b1[gc],        b1xr = b1[H_ + gc],        b1xh = b1[2 * H_ + gc];
    const float b1hz = b1[G3_ + gc],  b1hr = b1[G3_ + H_ + gc],  b1hh = b1[G3_ + 2 * H_ + gc];
    const float b2xz = b2[gc],        b2xr = b2[H_ + gc],        b2xh = b2[2 * H_ + gc];
    const float b2hz = b2[G3_ + gc],  b2hr = b2[G3_ + H_ + gc],  b2hh = b2[G3_ + 2 * H_ + gc];

    float h1m = 0.f, h2m = 0.f;   // fp32 masters, register-resident

    __shared__ float Cs[4][32][25];
    __shared__ float hs[256];

    const int m = mt * 16 + ln;       // batch row for A fragments

    for (int i = 0; i < NITER; ++i) {
        const int rb = (i + 1) & 1;
        const int wb = i & 1;
        const _Float16* h1r = packs + rb * PACK_ELEMS;
        const _Float16* h2r = packs + 2 * PACK_ELEMS + rb * PACK_ELEMS;
        _Float16* h1w = packs + wb * PACK_ELEMS;
        _Float16* h2w = packs + 2 * PACK_ELEMS + wb * PACK_ELEMS;

        // xn prefetch (no cross-WG dependency) issued before the barrier spin
        half8 ax0, ax1;
        if (i < T_) {
            ax0 = *reinterpret_cast<const half8*>(xn + ((size_t)i * B_ + m) * F_ + quad * 8);
            ax1 = *reinterpret_cast<const half8*>(xn + ((size_t)i * B_ + m) * F_ + 32 + quad * 8);
        }

        // barrier wait for generation i-1
        if (i >= 1) {
            if (tid < CNT_LINES) {
                const unsigned tgt = 4u * (unsigned)i;
                while (__hip_atomic_load(&cnt[tid * CNT_STRIDE], __ATOMIC_RELAXED,
                                         __HIP_MEMORY_SCOPE_AGENT) < tgt)
                    __builtin_amdgcn_s_sleep(1);
            }
            __syncthreads();
        }
        asm volatile("" ::: "memory");

        f32x4 c0 = {0.f, 0.f, 0.f, 0.f};
        f32x4 c1 = c0, c2 = c0, c3 = c0;

        if (i < T_) {   // xproj for layer-1 step i (K=64)
            c0 = __builtin_amdgcn_mfma_f32_16x16x32_f16(ax0, fk1[0], c0, 0, 0, 0);
            c0 = __builtin_amdgcn_mfma_f32_16x16x32_f16(ax1, fk1[1], c0, 0, 0, 0);
        }
#pragma unroll
        for (int ks = 0; ks < 8; ++ks) {   // h1[i-1] feeds rk1 (inner1) and k2 (x2)
            half8 a1 = pack_load16(h1r + m * H_ + ks * 32 + quad * 8);
            c1 = __builtin_amdgcn_mfma_f32_16x16x32_f16(a1, frk1[ks], c1, 0, 0, 0);
            c2 = __builtin_amdgcn_mfma_f32_16x16x32_f16(a1, fk2[ks],  c2, 0, 0, 0);
        }
#pragma unroll
        for (int ks = 0; ks < 8; ++ks) {   // h2[i-2] feeds rk2 (inner2)
            half8 a2 = pack_load16(h2r + m * H_ + ks * 32 + quad * 8);
            c3 = __builtin_amdgcn_mfma_f32_16x16x32_f16(a2, frk2[ks], c3, 0, 0, 0);
        }

        // C/D layout: col = lane&15, row = quad*4 + reg
        if (valid) {
            const int r0 = mt * 16 + quad * 4;
#pragma unroll
            for (int rr = 0; rr < 4; ++rr) {
                Cs[0][r0 + rr][lc] = c0[rr];
                Cs[1][r0 + rr][lc] = c1[rr];
                Cs[2][r0 + rr][lc] = c2[rr];
                Cs[3][r0 + rr][lc] = c3[rr];
            }
        }
        __syncthreads();

        if (i < T_) {   // layer-1 gate combine for step i
            const float xz = Cs[0][bb][jl]      + b1xz;
            const float xr = Cs[0][bb][8 + jl]  + b1xr;
            const float xh = Cs[0][bb][16 + jl] + b1xh;
            const float rz = Cs[1][bb][jl]      + b1hz;
            const float rr = Cs[1][bb][8 + jl]  + b1hr;
            const float rh = Cs[1][bb][16 + jl] + b1hh;
            const float z  = sigf(xz + rz);
            const float r  = sigf(xr + rr);
            const float hh = tanhfast(xh + r * rh);
            h1m = z * h1m + (1.f - z) * hh;
        }
        if (i >= 1) {   // layer-2 gate combine for step i-1
            const float xz = Cs[2][bb][jl]      + b2xz;
            const float xr = Cs[2][bb][8 + jl]  + b2xr;
            const float xh = Cs[2][bb][16 + jl] + b2xh;
            const float rz = Cs[3][bb][jl]      + b2hz;
            const float rr = Cs[3][bb][8 + jl]  + b2hr;
            const float rh = Cs[3][bb][16 + jl] + b2hh;
            const float z  = sigf(xz + rz);
            const float r  = sigf(xr + rr);
            const float hh = tanhfast(xh + r * rh);
            h2m = z * h2m + (1.f - z) * hh;
        }

        if (i < T_) {
            // pack 4 lanes' fp16 into 8B, coherent write-through store to IC
            const unsigned long long v1 = gather4(f16b(h1m), jl);
            const unsigned long long v2 = gather4(f16b(h2m), jl);
            if ((jl & 3) == 0) {
                __hip_atomic_store((unsigned long long*)(h1w + bb * H_ + w * 8 + jl), v1,
                                   __ATOMIC_RELAXED, __HIP_MEMORY_SCOPE_AGENT);
                __hip_atomic_store((unsigned long long*)(h2w + bb * H_ + w * 8 + jl), v2,
                                   __ATOMIC_RELAXED, __HIP_MEMORY_SCOPE_AGENT);
            }
            asm volatile("s_waitcnt vmcnt(0)" ::: "memory");  // per-wave store ack
            __syncthreads();                                   // all waves' stores done
            if (tid == 0)
                __hip_atomic_fetch_add(&cnt[(w & 7) * CNT_STRIDE], 1u,
                                       __ATOMIC_RELAXED, __HIP_MEMORY_SCOPE_AGENT);
        }
    }

    // ---- final dense: out[b][o] += sum_j h2[b][8w+j] * wd[8w+j][o]  (out pre-init to bd)
    hs[tid] = h2m;
    __syncthreads();
    const int o  = tid & 63;
    const int bq = tid >> 6;
    for (int pass = 0; pass < 8; ++pass) {
        const int b = pass * 4 + bq;
        float acc = 0.f;
#pragma unroll
        for (int j = 0; j < 8; ++j) acc += hs[b * 8 + j] * wd[(w * 8 + j) * OUT_ + o];
        atomicAdd(&out[b * OUT_ + o], acc);
    }
}

// ---------------------------------------------------------------------------
extern "C" void kernel_launch(void* const* d_in, const int* in_sizes, int n_in,
                              void* d_out, int out_size, void* d_ws, size_t ws_size,
                              hipStream_t stream) {
    const float* x     = (const float*)d_in[0];
    const float* gamma = (const float*)d_in[1];
    const float* beta  = (const float*)d_in[2];
    const float* k1    = (const float*)d_in[3];
    const float* rk1   = (const float*)d_in[4];
    const float* b1    = (const float*)d_in[5];
    const float* k2    = (const float*)d_in[6];
    const float* rk2   = (const float*)d_in[7];
    const float* b2    = (const float*)d_in[8];
    const float* bd    = (const float*)d_in[10];
    const float* wd    = (const float*)d_in[9];
    float* out = (float*)d_out;

    char* ws = (char*)d_ws;
    _Float16*     xn    = (_Float16*)ws;
    _Float16*     packs = (_Float16*)(ws + PACK_OFF);
    unsigned int* cnt   = (unsigned int*)(ws + CNT_OFF);

    hipLaunchKernelGGL(init_kernel, dim3(16), dim3(256), 0, stream, out, bd, packs, cnt);
    hipLaunchKernelGGL(ln_kernel, dim3(B_ * T_ / 16), dim3(256), 0, stream, x, gamma, beta, xn);

    void* args[] = {(void*)&xn, (void*)&k1, (void*)&rk1, (void*)&b1, (void*)&k2,
                    (void*)&rk2, (void*)&b2, (void*)&wd, (void*)&out, (void*)&packs, (void*)&cnt};
    hipLaunchCooperativeKernel((void*)gru_main, dim3(NWG), dim3(256), args, 0, stream);
}

// Round 3
// 9263.171 us; speedup vs baseline: 1.3115x; 1.3115x over previous
//
#include <hip/hip_runtime.h>

// Problem constants
#define B_    32
#define T_    2048
#define F_    64
#define H_    256
#define OUT_  64
#define G3_   768           // 3*H
#define NWG   16            // workgroups in the persistent GRU kernel
#define WGT   512           // threads per WG (8 waves)
#define NITER (T_ + 1)      // pipelined: iter i computes h1[i] and h2[i-1]

// ws layout (bytes)
#define XN_BYTES   (B_ * T_ * F_ * 2)            // 8,388,608  fp16 LN(x), [T][B][F]
#define PACK_OFF   XN_BYTES
#define PACK_ELEMS (B_ * H_)                     // 8192 fp16 per buffer
#define PACK_BYTES (4 * PACK_ELEMS * 2)          // h1[2 parity] + h2[2 parity]
#define CNT_OFF    (PACK_OFF + PACK_BYTES)

typedef _Float16 half8 __attribute__((ext_vector_type(8)));
typedef _Float16 half4 __attribute__((ext_vector_type(4)));
typedef float    f32x4 __attribute__((ext_vector_type(4)));
typedef unsigned long long u64;

__device__ __forceinline__ float sigf(float x) {
    x = fminf(fmaxf(x, -30.f), 30.f);
    return 1.f / (1.f + __expf(-x));
}
__device__ __forceinline__ float tanhfast(float x) {
    x = fminf(fmaxf(x, -15.f), 15.f);
    float e = __expf(2.f * x);
    return (e - 1.f) / (e + 1.f);
}
__device__ __forceinline__ unsigned short f16b(float f) {
    union { _Float16 h; unsigned short u; } c; c.h = (_Float16)f; return c.u;
}
// Gather 4 neighboring lanes' fp16 (jl, jl^1, jl^2, jl^3) into one u64 (LE by jl)
__device__ __forceinline__ u64 gather4(unsigned short u, int jl) {
    unsigned int p = (unsigned int)__shfl_xor((int)(unsigned int)u, 1);
    unsigned int lo32 = (jl & 1) ? ((p & 0xffffu) | ((unsigned int)u << 16))
                                 : ((unsigned int)u | (p << 16));
    unsigned int q = (unsigned int)__shfl_xor((int)lo32, 2);
    return (jl & 2) ? (((u64)lo32 << 32) | q)
                    : ((u64)lo32 | ((u64)q << 32));
}

// ---------------------------------------------------------------------------
// Init: zero barrier counter + h-pack buffers, out = bias broadcast
// ---------------------------------------------------------------------------
__global__ void init_kernel(float* __restrict__ out, const float* __restrict__ bd,
                            _Float16* __restrict__ packs, unsigned int* __restrict__ cnt) {
    int t = blockIdx.x * 256 + threadIdx.x;              // 16*256 = 4096 threads
    if (t < B_ * OUT_) out[t] = bd[t & (OUT_ - 1)];
    if (t < 16) cnt[t] = 0u;
    for (int p = t; p < 4 * PACK_ELEMS; p += 4096) packs[p] = (_Float16)0.f;
}

// ---------------------------------------------------------------------------
// LayerNorm over F=64, fp16 output TRANSPOSED to [T][B][F].
// ---------------------------------------------------------------------------
__global__ __launch_bounds__(256) void ln_kernel(const float* __restrict__ x,
                                                 const float* __restrict__ gamma,
                                                 const float* __restrict__ beta,
                                                 _Float16* __restrict__ xn) {
    const int tid = threadIdx.x;
    const int r = tid >> 4, q = tid & 15;
    const size_t row = (size_t)blockIdx.x * 16 + r;      // = b*T + t
    const int b = (int)(row >> 11);
    const int t = (int)(row & 2047);
    const float4 v  = *(const float4*)(x + row * F_ + q * 4);
    const float4 g  = *(const float4*)(gamma + q * 4);
    const float4 be = *(const float4*)(beta + q * 4);
    float s = v.x + v.y + v.z + v.w;
    s += __shfl_xor(s, 1, 16); s += __shfl_xor(s, 2, 16);
    s += __shfl_xor(s, 4, 16); s += __shfl_xor(s, 8, 16);
    const float mu = s * (1.f / 64.f);
    const float dx = v.x - mu, dy = v.y - mu, dz = v.z - mu, dw = v.w - mu;
    float qq = dx * dx + dy * dy + dz * dz + dw * dw;
    qq += __shfl_xor(qq, 1, 16); qq += __shfl_xor(qq, 2, 16);
    qq += __shfl_xor(qq, 4, 16); qq += __shfl_xor(qq, 8, 16);
    const float rs = rsqrtf(qq * (1.f / 64.f) + 1e-3f);
    half4 o;
    o[0] = (_Float16)(dx * rs * g.x + be.x);
    o[1] = (_Float16)(dy * rs * g.y + be.y);
    o[2] = (_Float16)(dz * rs * g.z + be.z);
    o[3] = (_Float16)(dw * rs * g.w + be.w);
    *(half4*)(xn + ((size_t)t * B_ + b) * F_ + q * 4) = o;
}

// ---------------------------------------------------------------------------
// Persistent fused 2-layer GRU scan + final dense. 16 WGs x 512 (cooperative).
// WG w owns h-cols [16w,16w+16) of both layers. 8 waves: mt=wave&1 (batch
// half), nt=wave>>1 (16-col tile of the 48 gate-cols); lc<48 valid.
// Packs staged once per WG into LDS; A-frags via ds_read_b128.
// Barrier: one monotonic counter, target 16*i, one poller/WG.
// ---------------------------------------------------------------------------
__global__ __launch_bounds__(WGT) void gru_main(
    const _Float16* __restrict__ xn,
    const float* __restrict__ k1, const float* __restrict__ rk1,
    const float* __restrict__ b1, const float* __restrict__ k2,
    const float* __restrict__ rk2, const float* __restrict__ b2,
    const float* __restrict__ wd, float* __restrict__ out,
    _Float16* __restrict__ packs, unsigned int* __restrict__ cnt) {
    const int w    = blockIdx.x;         // 0..15
    const int tid  = threadIdx.x;
    const int lane = tid & 63;
    const int wave = tid >> 6;           // 8 waves
    const int mt   = wave & 1;
    const int nt   = wave >> 1;          // 0..3
    const int ln   = lane & 15;
    const int quad = lane >> 4;

    // ---- B-operand fragments: lane holds B[k=quad*8+j][n=lane&15]
    // local col lc in [0,48): gate = lc>>4, hidx = lc&15 -> global col gate*256 + 16w + hidx
    const int  lc    = nt * 16 + ln;
    const bool valid = (lc < 48);
    const int  gate  = lc >> 4;
    const int  hidx  = lc & 15;
    const int  gcol  = valid ? (gate * H_ + w * 16 + hidx) : 0;

    half8 fk1[2], frk1[8], fk2[8], frk2[8];
#pragma unroll
    for (int ks = 0; ks < 2; ++ks) {
        half8 f;
#pragma unroll
        for (int j = 0; j < 8; ++j) {
            const int k = ks * 32 + quad * 8 + j;
            const float v = k1[k * G3_ + gcol];
            f[j] = valid ? (_Float16)v : (_Float16)0.f;
        }
        fk1[ks] = f;
    }
#pragma unroll
    for (int ks = 0; ks < 8; ++ks) {
        half8 f1, f2, f3;
#pragma unroll
        for (int j = 0; j < 8; ++j) {
            const int k = ks * 32 + quad * 8 + j;
            const float v1 = rk1[k * G3_ + gcol];
            const float v2 = k2 [k * G3_ + gcol];
            const float v3 = rk2[k * G3_ + gcol];
            f1[j] = valid ? (_Float16)v1 : (_Float16)0.f;
            f2[j] = valid ? (_Float16)v2 : (_Float16)0.f;
            f3[j] = valid ? (_Float16)v3 : (_Float16)0.f;
        }
        frk1[ks] = f1; fk2[ks] = f2; frk2[ks] = f3;
    }

    // ---- gate-phase mapping: thread -> (batch bb, local col jl), one h per layer
    const int jl = tid & 15;
    const int bb = tid >> 4;             // 0..31
    const int gc = w * 16 + jl;
    const float b1xz = b1[gc],        b1xr = b1[H_ + gc],        b1xh = b1[2 * H_ + gc];
    const float b1hz = b1[G3_ + gc],  b1hr = b1[G3_ + H_ + gc],  b1hh = b1[G3_ + 2 * H_ + gc];
    const float b2xz = b2[gc],        b2xr = b2[H_ + gc],        b2xh = b2[2 * H_ + gc];
    const float b2hz = b2[G3_ + gc],  b2hr = b2[G3_ + H_ + gc],  b2hh = b2[G3_ + 2 * H_ + gc];

    float h1m = 0.f, h2m = 0.f;

    __shared__ _Float16 h1s[32][264];    // 256 + 8 pad halfs (528B row, 2-way banks)
    __shared__ _Float16 h2s[32][264];
    __shared__ float Cs[4][32][52];      // [xproj, inner1, x2, inner2][batch][col]
    __shared__ float hs[32][16];

    const int m = mt * 16 + ln;          // batch row for A fragments

    // staging mapping: thread -> (buffer sel, batch row sb, 64B segment)
    const int sel = tid >> 8;            // 0: h1, 1: h2
    const int sb  = (tid & 255) >> 3;
    const int seg = tid & 7;

    for (int i = 0; i < NITER; ++i) {
        const int rb = (i + 1) & 1;
        const int wb = i & 1;
        const _Float16* h1r = packs + rb * PACK_ELEMS;
        const _Float16* h2r = packs + 2 * PACK_ELEMS + rb * PACK_ELEMS;
        _Float16* h1w = packs + wb * PACK_ELEMS;
        _Float16* h2w = packs + 2 * PACK_ELEMS + wb * PACK_ELEMS;

        // ---- xproj (no cross-WG dependency): issue before the barrier wait
        f32x4 c0 = {0.f, 0.f, 0.f, 0.f};
        if (i < T_) {
            half8 ax0 = *reinterpret_cast<const half8*>(xn + ((size_t)i * B_ + m) * F_ + quad * 8);
            half8 ax1 = *reinterpret_cast<const half8*>(xn + ((size_t)i * B_ + m) * F_ + 32 + quad * 8);
            c0 = __builtin_amdgcn_mfma_f32_16x16x32_f16(ax0, fk1[0], c0, 0, 0, 0);
            c0 = __builtin_amdgcn_mfma_f32_16x16x32_f16(ax1, fk1[1], c0, 0, 0, 0);
        }

        // ---- barrier: wait for generation i-1 publication
        if (i >= 1) {
            if (tid == 0) {
                const unsigned tgt = (unsigned)(NWG * i);
                while (__hip_atomic_load(&cnt[0], __ATOMIC_RELAXED,
                                         __HIP_MEMORY_SCOPE_AGENT) < tgt)
                    __builtin_amdgcn_s_sleep(1);
            }
            __syncthreads();
        }
        asm volatile("" ::: "memory");

        // ---- stage packs -> LDS (coherent sc loads, 64B per thread)
        {
            const _Float16* sp = (sel ? h2r : h1r) + sb * H_ + seg * 32;
            _Float16* dp = sel ? &h2s[sb][seg * 32] : &h1s[sb][seg * 32];
            u64 q[8];
#pragma unroll
            for (int k = 0; k < 8; ++k)
                q[k] = __hip_atomic_load((const u64*)sp + k, __ATOMIC_RELAXED,
                                         __HIP_MEMORY_SCOPE_AGENT);
#pragma unroll
            for (int k = 0; k < 8; ++k)
                *((u64*)dp + k) = q[k];
        }
        __syncthreads();

        f32x4 c1 = {0.f, 0.f, 0.f, 0.f};
        f32x4 c2 = c1, c3 = c1;
#pragma unroll
        for (int ks = 0; ks < 8; ++ks) {   // h1[i-1] feeds rk1 (inner1) and k2 (x2)
            half8 a1 = *reinterpret_cast<const half8*>(&h1s[m][ks * 32 + quad * 8]);
            c1 = __builtin_amdgcn_mfma_f32_16x16x32_f16(a1, frk1[ks], c1, 0, 0, 0);
            c2 = __builtin_amdgcn_mfma_f32_16x16x32_f16(a1, fk2[ks],  c2, 0, 0, 0);
        }
#pragma unroll
        for (int ks = 0; ks < 8; ++ks) {   // h2[i-2] feeds rk2 (inner2)
            half8 a2 = *reinterpret_cast<const half8*>(&h2s[m][ks * 32 + quad * 8]);
            c3 = __builtin_amdgcn_mfma_f32_16x16x32_f16(a2, frk2[ks], c3, 0, 0, 0);
        }

        // C/D layout: col = lane&15, row = quad*4 + reg
        if (valid) {
            const int r0 = mt * 16 + quad * 4;
#pragma unroll
            for (int rr = 0; rr < 4; ++rr) {
                Cs[0][r0 + rr][lc] = c0[rr];
                Cs[1][r0 + rr][lc] = c1[rr];
                Cs[2][r0 + rr][lc] = c2[rr];
                Cs[3][r0 + rr][lc] = c3[rr];
            }
        }
        __syncthreads();

        if (i < T_) {   // layer-1 gate combine for step i
            const float xz = Cs[0][bb][jl]      + b1xz;
            const float xr = Cs[0][bb][16 + jl] + b1xr;
            const float xh = Cs[0][bb][32 + jl] + b1xh;
            const float rz = Cs[1][bb][jl]      + b1hz;
            const float rr = Cs[1][bb][16 + jl] + b1hr;
            const float rh = Cs[1][bb][32 + jl] + b1hh;
            const float z  = sigf(xz + rz);
            const float r  = sigf(xr + rr);
            const float hh = tanhfast(xh + r * rh);
            h1m = z * h1m + (1.f - z) * hh;
        }
        if (i >= 1) {   // layer-2 gate combine for step i-1
            const float xz = Cs[2][bb][jl]      + b2xz;
            const float xr = Cs[2][bb][16 + jl] + b2xr;
            const float xh = Cs[2][bb][32 + jl] + b2xh;
            const float rz = Cs[3][bb][jl]      + b2hz;
            const float rr = Cs[3][bb][16 + jl] + b2hr;
            const float rh = Cs[3][bb][32 + jl] + b2hh;
            const float z  = sigf(xz + rz);
            const float r  = sigf(xr + rr);
            const float hh = tanhfast(xh + r * rh);
            h2m = z * h2m + (1.f - z) * hh;
        }

        if (i < T_) {
            // publish: pack 4 lanes' fp16 into 8B coherent stores to IC
            const u64 v1 = gather4(f16b(h1m), jl);
            const u64 v2 = gather4(f16b(h2m), jl);
            if ((jl & 3) == 0) {
                __hip_atomic_store((u64*)(h1w + bb * H_ + w * 16 + jl), v1,
                                   __ATOMIC_RELAXED, __HIP_MEMORY_SCOPE_AGENT);
                __hip_atomic_store((u64*)(h2w + bb * H_ + w * 16 + jl), v2,
                                   __ATOMIC_RELAXED, __HIP_MEMORY_SCOPE_AGENT);
            }
            asm volatile("s_waitcnt vmcnt(0)" ::: "memory");  // per-wave store ack
            __syncthreads();                                   // all waves' stores done
            if (tid == 0)
                __hip_atomic_fetch_add(&cnt[0], 1u,
                                       __ATOMIC_RELAXED, __HIP_MEMORY_SCOPE_AGENT);
        }
    }

    // ---- final dense: out[b][o] += sum_j h2[b][16w+j] * wd[16w+j][o]
    hs[bb][jl] = h2m;
    __syncthreads();
    const int o  = tid & 63;
    const int bq = tid >> 6;             // 0..7
    for (int pass = 0; pass < 4; ++pass) {
        const int b = pass * 8 + bq;
        float acc = 0.f;
#pragma unroll
        for (int j = 0; j < 16; ++j) acc += hs[b][j] * wd[(w * 16 + j) * OUT_ + o];
        atomicAdd(&out[b * OUT_ + o], acc);
    }
}

// ---------------------------------------------------------------------------
extern "C" void kernel_launch(void* const* d_in, const int* in_sizes, int n_in,
                              void* d_out, int out_size, void* d_ws, size_t ws_size,
                              hipStream_t stream) {
    const float* x     = (const float*)d_in[0];
    const float* gamma = (const float*)d_in[1];
    const float* beta  = (const float*)d_in[2];
    const float* k1    = (const float*)d_in[3];
    const float* rk1   = (const float*)d_in[4];
    const float* b1    = (const float*)d_in[5];
    const float* k2    = (const float*)d_in[6];
    const float* rk2   = (const float*)d_in[7];
    const float* b2    = (const float*)d_in[8];
    const float* wd    = (const float*)d_in[9];
    const float* bd    = (const float*)d_in[10];
    float* out = (float*)d_out;

    char* ws = (char*)d_ws;
    _Float16*     xn    = (_Float16*)ws;
    _Float16*     packs = (_Float16*)(ws + PACK_OFF);
    unsigned int* cnt   = (unsigned int*)(ws + CNT_OFF);

    hipLaunchKernelGGL(init_kernel, dim3(16), dim3(256), 0, stream, out, bd, packs, cnt);
    hipLaunchKernelGGL(ln_kernel, dim3(B_ * T_ / 16), dim3(256), 0, stream, x, gamma, beta, xn);

    void* args[] = {(void*)&xn, (void*)&k1, (void*)&rk1, (void*)&b1, (void*)&k2,
                    (void*)&rk2, (void*)&b2, (void*)&wd, (void*)&out, (void*)&packs, (void*)&cnt};
    hipLaunchCooperativeKernel((void*)gru_main, dim3(NWG), dim3(WGT), args, 0, stream);
}